// Round 7
// baseline (162.277 us; speedup 1.0000x reference)
//
#include <hip/hip_runtime.h>
#include <stdint.h>

#define BS 8192
#define DD 128
#define L2E 1.4426950408889634f
#define LN2 0.6931471805599453f

typedef __attribute__((ext_vector_type(8))) short short8;
typedef __attribute__((ext_vector_type(4))) float float4v;

#if __has_builtin(__builtin_amdgcn_exp2f)
#define EXP2(x) __builtin_amdgcn_exp2f(x)
#else
#define EXP2(x) exp2f(x)
#endif

__device__ __forceinline__ float bf2f(short s) {
  union { unsigned u; float f; } c;
  c.u = ((unsigned)(unsigned short)s) << 16;
  return c.f;
}
__device__ __forceinline__ short f2bf(float f) {
  union { float f; unsigned u; } c; c.f = f;
  unsigned u = c.u + 0x7FFFu + ((c.u >> 16) & 1u);
  return (short)(u >> 16);
}

// Fragment-ordered bf16 layout ("xnbF"): 16-byte chunk index for (row, kc):
//   chunk(row,kc) = (row>>4)*256 + (kc>>2)*64 + (kc&3)*16 + (row&15)
// A wave load F[g*256 + t*64 + lane] gives lane (quad=lane>>4, col=lane&15) the
// 8 bf16 of row g*16+col, k-chunk 4t+quad — the verified mfma_f32_16x16x32_bf16
// A/B fragment layout (rounds 2-6 passed absmax=0 with it). A 64-col panel is
// 1024 CONTIGUOUS chunks -> linear 16KB global_load_lds staging, conflict-free
// lane-contiguous ds_read_b128.

// K1: normalize rows -> xnbF, per-class column sums (register-accumulated, then
// LDS, then 16-way-split global atomics: chain 32), counts, mask mf, zero-init.
// 512 blocks (2 waves/SIMD) x 16 rows.
__global__ __launch_bounds__(256) void k_norm(const float* __restrict__ data,
                                              const int* __restrict__ label,
                                              char* __restrict__ xnbF,
                                              float* __restrict__ gh16,
                                              int* __restrict__ cnt16,
                                              float* __restrict__ Zr,
                                              float* __restrict__ Ur,
                                              float* __restrict__ Vr,
                                              float* __restrict__ mf) {
  __shared__ float shg[256];
  __shared__ int shc[2];
  int tid = threadIdx.x, wave = tid >> 6, lane = tid & 63;
  int lh = lane & 31, rsel = lane >> 5;
  if (tid < 2) shc[tid] = 0;
  shg[tid] = 0.f;
  int rowbase = blockIdx.x * 16;
  if (tid < 16) {  // zero this block's accumulator rows (workspace is poisoned)
    int row = rowbase + tid;
    Zr[row] = 0.f; Ur[row] = 0.f; Vr[row] = 0.f;
    mf[row] = (label[row] == 0) ? 1.f : 0.f;
  }
  __syncthreads();

  float a00 = 0.f, a01 = 0.f, a02 = 0.f, a03 = 0.f;  // class-0 column partials
  float a10 = 0.f, a11 = 0.f, a12 = 0.f, a13 = 0.f;  // class-1
  int c0 = 0, c1 = 0;
#pragma unroll
  for (int it = 0; it < 2; ++it) {
    int row = rowbase + it * 8 + wave * 2 + rsel;
    float4 v = *(const float4*)&data[row * DD + lh * 4];  // 16B/lane coalesced
    float ss = v.x * v.x + v.y * v.y + v.z * v.z + v.w * v.w;
#pragma unroll
    for (int off = 16; off; off >>= 1) ss += __shfl_xor(ss, off);  // 32-lane
    float rn = 1.f / fmaxf(sqrtf(ss), 1e-12f);  // F.normalize eps clamp
    float x0 = v.x * rn, x1 = v.y * rn, x2 = v.z * rn, x3 = v.w * rn;

    unsigned pk0 = (unsigned)(unsigned short)f2bf(x0) |
                   ((unsigned)(unsigned short)f2bf(x1) << 16);
    unsigned pk1 = (unsigned)(unsigned short)f2bf(x2) |
                   ((unsigned)(unsigned short)f2bf(x3) << 16);
    int kc = lh >> 1;
    size_t chunk = (size_t)(row >> 4) * 256 + (size_t)(kc >> 2) * 64 +
                   (size_t)(kc & 3) * 16 + (row & 15);
    *(uint2*)(xnbF + chunk * 16 + (lh & 1) * 8) = make_uint2(pk0, pk1);

    int lab = label[row];  // half-wave uniform
    if (lab == 0) {
      a00 += x0; a01 += x1; a02 += x2; a03 += x3;
      if (lh == 0) c0++;
    } else {
      a10 += x0; a11 += x1; a12 += x2; a13 += x3;
      if (lh == 0) c1++;
    }
  }
  int base = lh * 4;
  atomicAdd(&shg[base + 0], a00); atomicAdd(&shg[base + 1], a01);
  atomicAdd(&shg[base + 2], a02); atomicAdd(&shg[base + 3], a03);
  atomicAdd(&shg[128 + base + 0], a10); atomicAdd(&shg[128 + base + 1], a11);
  atomicAdd(&shg[128 + base + 2], a12); atomicAdd(&shg[128 + base + 3], a13);
  if (lh == 0) { atomicAdd(&shc[0], c0); atomicAdd(&shc[1], c1); }
  __syncthreads();
  // 16-way-split targets: per-address global atomic chain is 512/16 = 32
  atomicAdd(&gh16[(blockIdx.x & 15) * 256 + tid], shg[tid]);
  if (tid < 2) atomicAdd(&cnt16[(blockIdx.x & 15) * 2 + tid], shc[tid]);
}

// K3: SYMMETRIC Gram-row reductions (e_ij = e_ji; e*l symmetric too).
// Only the upper-triangle tiles are computed: 528 tiles of 256x256, split into
// 1056 jobs of 256 rows x 128 cols (tail-balance: 1056 ~ 2*512 resident slots).
// Off-diagonal jobs emit BOTH row-sums (rows I, summed over cols J) and, via
// in-register column-sums + symmetry, the transposed contributions to rows J.
// Col-direction V weights by the ROW mask m_i; row-direction V by the col mask.
// Work drops to 51.6% of the full matrix. Diagonal tiles emit row-sums only.
__global__ __launch_bounds__(512, 4) void k_main(const short* __restrict__ xnbF,
                                                 const int* __restrict__ label,
                                                 const float* __restrict__ mf,
                                                 const float* __restrict__ scale,
                                                 float* __restrict__ Zr,
                                                 float* __restrict__ Ur,
                                                 float* __restrict__ Vr) {
  __shared__ short tile[2][64 * DD];  // 2 x 16KB double buffer
  int tid = threadIdx.x, wave = tid >> 6, lane = tid & 63;
  int quad = lane >> 4, col = lane & 15;
  // job -> (tile t, half h) -> triangular (bi, bj)
  int job = blockIdx.x;
  int t = job >> 1, half = job & 1;
  int bi = 0, rem = t;
  while (rem >= 32 - bi) { rem -= 32 - bi; ++bi; }  // uniform, <=32 iters
  int bj = bi + rem;
  bool offd = (bi != bj);
  float se2 = __expf(scale[0]) * L2E;  // exp(scale)*log2(e): log2-domain logits

  const short8* F = (const short8*)xnbF;  // indexed by 16B chunk

  // A fragments: 2 row-sets of 16 rows (32 rows/wave); scaled by se2 once.
  int gA = bi * 16 + wave * 2;
  short8 af[2][4];
#pragma unroll
  for (int s = 0; s < 2; ++s)
#pragma unroll
    for (int tt = 0; tt < 4; ++tt) {
      short8 a = F[(size_t)(gA + s) * 256 + tt * 64 + lane];
#pragma unroll
      for (int i = 0; i < 8; ++i) a[i] = f2bf(bf2f(a[i]) * se2);
      af[s][tt] = a;
    }

  // row masks (class-0 indicator of this wave's rows) for col-direction V
  int rowb = bi * 256 + wave * 32;
  float mr0[4], mr1[4];
#pragma unroll
  for (int r = 0; r < 4; ++r) {
    mr0[r] = mf[rowb + quad * 4 + r];
    mr1[r] = mf[rowb + 16 + quad * 4 + r];
  }

  float4v Z0 = {0.f,0.f,0.f,0.f}, Z1 = Z0, U0 = Z0, U1 = Z0, V0 = Z0, V1 = Z0;

  int cgb = bj * 16 + half * 8;      // chunk-group base (2 subtiles of 4 cgs)
  int jbase = bj * 256 + half * 128;

#define STAGE(buf, st)                                                         \
  {                                                                            \
    const char* s_ = (const char*)xnbF +                                       \
                     ((size_t)(cgb + (st) * 4) * 256 + tid) * 16;              \
    char* d_ = (char*)tile[buf] + tid * 16;                                    \
    __builtin_amdgcn_global_load_lds(                                          \
        (const __attribute__((address_space(1))) void*)(uintptr_t)s_,          \
        (__attribute__((address_space(3))) void*)(uintptr_t)d_, 16, 0, 0);     \
    __builtin_amdgcn_global_load_lds(                                          \
        (const __attribute__((address_space(1))) void*)(uintptr_t)(s_ + 8192), \
        (__attribute__((address_space(3))) void*)(uintptr_t)(d_ + 8192),       \
        16, 0, 0);                                                             \
  }

  STAGE(0, 0);
  __syncthreads();  // tile 0 resident

#pragma unroll 1
  for (int st = 0; st < 2; ++st) {
    if (st == 0) STAGE(1, 1);  // in flight over subtile 0's compute
    const short8* T8 = (const short8*)tile[st];
    int jcb = jbase + st * 64;
#pragma unroll
    for (int jo = 0; jo < 4; ++jo) {
      short8 b0 = T8[jo * 256 + lane];
      short8 b1 = T8[jo * 256 + 64 + lane];
      short8 b2 = T8[jo * 256 + 128 + lane];
      short8 b3 = T8[jo * 256 + 192 + lane];
      float m0 = mf[jcb + jo * 16 + col];  // col class-0 mask (per lane)
      float4v c0 = {0.f, 0.f, 0.f, 0.f}, c1 = c0;
      c0 = __builtin_amdgcn_mfma_f32_16x16x32_bf16(af[0][0], b0, c0, 0, 0, 0);
      c1 = __builtin_amdgcn_mfma_f32_16x16x32_bf16(af[1][0], b0, c1, 0, 0, 0);
      c0 = __builtin_amdgcn_mfma_f32_16x16x32_bf16(af[0][1], b1, c0, 0, 0, 0);
      c1 = __builtin_amdgcn_mfma_f32_16x16x32_bf16(af[1][1], b1, c1, 0, 0, 0);
      c0 = __builtin_amdgcn_mfma_f32_16x16x32_bf16(af[0][2], b2, c0, 0, 0, 0);
      c1 = __builtin_amdgcn_mfma_f32_16x16x32_bf16(af[1][2], b2, c1, 0, 0, 0);
      c0 = __builtin_amdgcn_mfma_f32_16x16x32_bf16(af[0][3], b3, c0, 0, 0, 0);
      c1 = __builtin_amdgcn_mfma_f32_16x16x32_bf16(af[1][3], b3, c1, 0, 0, 0);
      float zc = 0.f, uc = 0.f, vc = 0.f;  // column partials (this wave's rows)
#pragma unroll
      for (int r = 0; r < 4; ++r) {  // C/D: col=lane&15, row=quad*4+r (m89)
        float l = c0[r], e = EXP2(l);  // log2-domain, |l|<=20.6: fp32-safe
        Z0[r] += e; U0[r] = fmaf(e, l, U0[r]); V0[r] = fmaf(m0, e, V0[r]);
        zc += e; uc = fmaf(e, l, uc); vc = fmaf(mr0[r], e, vc);
        l = c1[r]; e = EXP2(l);
        Z1[r] += e; U1[r] = fmaf(e, l, U1[r]); V1[r] = fmaf(m0, e, V1[r]);
        zc += e; uc = fmaf(e, l, uc); vc = fmaf(mr1[r], e, vc);
      }
      if (offd) {  // transpose contributions: cols J become rows via symmetry
        zc += __shfl_xor(zc, 16); uc += __shfl_xor(uc, 16);
        vc += __shfl_xor(vc, 16);
        zc += __shfl_xor(zc, 32); uc += __shfl_xor(uc, 32);
        vc += __shfl_xor(vc, 32);
        if (quad == 0) {  // lanes 0..15: one col each
          int jc = jcb + jo * 16 + col;
          atomicAdd(&Zr[jc], zc);
          atomicAdd(&Ur[jc], uc * LN2);  // log2-domain -> nats
          float vcol = (m0 != 0.f) ? vc : (zc - vc);  // same-class sum for j
          atomicAdd(&Vr[jc], vcol);
        }
      }
    }
    __syncthreads();  // st=0: drains STAGE(1); st=1: harmless
  }
#undef STAGE

  // row-direction: reduce across the 16 column-lanes sharing each output row
#define EMIT(s, Zc, Uc, Vc)                                                    \
  {                                                                            \
    _Pragma("unroll")                                                          \
    for (int r = 0; r < 4; ++r) {                                              \
      float z = Zc[r], u = Uc[r], v0 = Vc[r];                                  \
      _Pragma("unroll")                                                        \
      for (int off = 1; off < 16; off <<= 1) {                                 \
        z += __shfl_xor(z, off);                                               \
        u += __shfl_xor(u, off);                                               \
        v0 += __shfl_xor(v0, off);                                             \
      }                                                                        \
      if (col == 0) {                                                          \
        int row = rowb + s * 16 + quad * 4 + r;                                \
        int lab = label[row];                                                  \
        float v = (lab == 0) ? v0 : (z - v0);                                  \
        atomicAdd(&Zr[row], z);                                                \
        atomicAdd(&Ur[row], u * LN2); /* log2-domain -> nats */                \
        atomicAdd(&Vr[row], v);                                                \
      }                                                                        \
    }                                                                          \
  }
  EMIT(0, Z0, U0, V0)
  EMIT(1, Z1, U1, V1)
#undef EMIT
}

// K4: per-row loss; S,T via closed-form dots with class sums. 512 blocks x 16
// rows; per-block partial + agent-scope last-block ticket does the final sum.
__global__ __launch_bounds__(256) void k_final(const float* __restrict__ data,
                                               const int* __restrict__ label,
                                               const float* __restrict__ scale,
                                               const float* __restrict__ gh16,
                                               const int* __restrict__ cnt16,
                                               const float* __restrict__ Zr,
                                               const float* __restrict__ Ur,
                                               const float* __restrict__ Vr,
                                               float* __restrict__ partial,
                                               int* __restrict__ ticket,
                                               float* __restrict__ out) {
  __shared__ float hsum[256];
  __shared__ float bsum[4];
  __shared__ int lastb;
  int tid = threadIdx.x, wave = tid >> 6, lane = tid & 63;
  int lh = lane & 31, rsel = lane >> 5;
  float hs = 0.f;
#pragma unroll
  for (int i = 0; i < 16; ++i) hs += gh16[i * 256 + tid];
  hsum[tid] = hs;
  __syncthreads();

  float se = __expf(scale[0]);
  int ci0 = 0, ci1 = 0;
#pragma unroll
  for (int i = 0; i < 16; ++i) { ci0 += cnt16[2 * i]; ci1 += cnt16[2 * i + 1]; }
  float c0 = (float)ci0, c1 = (float)ci1;
  float4 h0 = *(const float4*)&hsum[lh * 4];
  float4 h1 = *(const float4*)&hsum[128 + lh * 4];

  float local = 0.f;
#pragma unroll
  for (int it = 0; it < 2; ++it) {
    int row = blockIdx.x * 16 + it * 8 + wave * 2 + rsel;
    float4 v = *(const float4*)&data[row * DD + lh * 4];
    float ss = v.x * v.x + v.y * v.y + v.z * v.z + v.w * v.w;
#pragma unroll
    for (int off = 16; off; off >>= 1) ss += __shfl_xor(ss, off);
    float rn = 1.f / fmaxf(sqrtf(ss), 1e-12f);

    int lab = label[row];
    float sg = v.x * (h0.x + h1.x) + v.y * (h0.y + h1.y) +
               v.z * (h0.z + h1.z) + v.w * (h0.w + h1.w);
    float sh_ = (lab == 0)
                    ? (v.x * h0.x + v.y * h0.y + v.z * h0.z + v.w * h0.w)
                    : (v.x * h1.x + v.y * h1.y + v.z * h1.z + v.w * h1.w);
#pragma unroll
    for (int off = 16; off; off >>= 1) {
      sg += __shfl_xor(sg, off);
      sh_ += __shfl_xor(sh_, off);
    }
    if (lh == 0) {
      float cc = (lab == 0) ? c0 : c1;
      float a = __expf(1.f / cc);
      float Zq = cc * a + ((float)BS - cc);
      float S = se * sg * rn, T = se * sh_ * rn;
      float Zv = Zr[row], Uv = Ur[row], Vv = Vr[row];
      // loss_i = a/Zq - (S+(a-1)T)/Zq + U/Z - V/(c*Z)  (M_i, log Zq cancelled)
      local += a / Zq - (S + (a - 1.f) * T) / Zq + Uv / Zv - Vv / (cc * Zv);
    }
  }
  // local is nonzero only on lanes 0 and 32; full-wave reduce is safe
#pragma unroll
  for (int off = 32; off; off >>= 1) local += __shfl_xor(local, off);
  if (lane == 0) bsum[wave] = local;
  __syncthreads();
  if (tid == 0) {
    float psum = bsum[0] + bsum[1] + bsum[2] + bsum[3];
    __hip_atomic_store(&partial[blockIdx.x], psum, __ATOMIC_RELEASE,
                       __HIP_MEMORY_SCOPE_AGENT);
    int t = __hip_atomic_fetch_add(ticket, 1, __ATOMIC_ACQ_REL,
                                   __HIP_MEMORY_SCOPE_AGENT);
    lastb = (t == 511);
  }
  __syncthreads();
  if (lastb) {  // last block sums all 512 partials and stores the result
    float v = __hip_atomic_load(&partial[tid], __ATOMIC_ACQUIRE,
                                __HIP_MEMORY_SCOPE_AGENT) +
              __hip_atomic_load(&partial[tid + 256], __ATOMIC_ACQUIRE,
                                __HIP_MEMORY_SCOPE_AGENT);
#pragma unroll
    for (int off = 32; off; off >>= 1) v += __shfl_xor(v, off);
    if (lane == 0) bsum[wave] = v;
    __syncthreads();
    if (tid == 0)
      out[0] = (bsum[0] + bsum[1] + bsum[2] + bsum[3]) * (0.5f / (float)BS);
  }
}

extern "C" void kernel_launch(void* const* d_in, const int* in_sizes, int n_in,
                              void* d_out, int out_size, void* d_ws, size_t ws_size,
                              hipStream_t stream) {
  const float* data = (const float*)d_in[0];
  const float* scale = (const float*)d_in[1];
  const int* label = (const int*)d_in[2];
  char* ws = (char*)d_ws;
  // ws layout (bytes):
  //   0        xnbF bf16 fragment-order [8192*128]   2 MB
  //   2097152  Zr      f32 [8192]
  //   2129920  Ur      f32 [8192]
  //   2162688  Vr      f32 [8192]
  //   2195456  gh16    f32 [16][256]  (16-way split class sums)
  //   2211840  cnt16   int [32]       (16-way split class counts)
  //   2211968  ticket  int [1]
  //   2211972  partial f32 [512]
  //   2214020  mf      f32 [8192]
  char* xnbF = ws;
  float* Zr = (float*)(ws + 2097152);
  float* Ur = (float*)(ws + 2129920);
  float* Vr = (float*)(ws + 2162688);
  float* gh16 = (float*)(ws + 2195456);
  int* cnt16 = (int*)(ws + 2211840);
  int* ticket = (int*)(ws + 2211968);
  float* partial = (float*)(ws + 2211972);
  float* mf = (float*)(ws + 2214020);

  // gh16+cnt16+ticket (16516 B); Zr/Ur/Vr/mf zeroed in k_norm; partial fully
  // written by k_final before any read; out stored by k_final's last block.
  hipMemsetAsync(ws + 2195456, 0, 16516, stream);

  k_norm<<<512, 256, 0, stream>>>(data, label, xnbF, gh16, cnt16, Zr, Ur, Vr, mf);
  k_main<<<1056, 512, 0, stream>>>((const short*)xnbF, label, mf, scale, Zr, Ur, Vr);
  k_final<<<512, 256, 0, stream>>>(data, label, scale, gh16, cnt16, Zr, Ur, Vr,
                                   partial, ticket, (float*)d_out);
}

// Round 8
// 150.609 us; speedup vs baseline: 1.0775x; 1.0775x over previous
//
#include <hip/hip_runtime.h>
#include <stdint.h>

#define BS 8192
#define DD 128
#define L2E 1.4426950408889634f
#define LN2 0.6931471805599453f

typedef __attribute__((ext_vector_type(8))) short short8;
typedef __attribute__((ext_vector_type(4))) float float4v;

#if __has_builtin(__builtin_amdgcn_exp2f)
#define EXP2(x) __builtin_amdgcn_exp2f(x)
#else
#define EXP2(x) exp2f(x)
#endif

__device__ __forceinline__ float bf2f(short s) {
  union { unsigned u; float f; } c;
  c.u = ((unsigned)(unsigned short)s) << 16;
  return c.f;
}
__device__ __forceinline__ short f2bf(float f) {
  union { float f; unsigned u; } c; c.f = f;
  unsigned u = c.u + 0x7FFFu + ((c.u >> 16) & 1u);
  return (short)(u >> 16);
}

// Fragment-ordered bf16 layout ("xnbF"): 16-byte chunk index for (row, kc):
//   chunk(row,kc) = (row>>4)*256 + (kc>>2)*64 + (kc&3)*16 + (row&15)
// A wave load F[g*256 + t*64 + lane] gives lane (quad=lane>>4, col=lane&15) the
// 8 bf16 of row g*16+col, k-chunk 4t+quad — the verified mfma_f32_16x16x32_bf16
// A/B fragment layout (rounds 2-7 passed absmax=0 with it). A 64-col panel is
// 1024 CONTIGUOUS chunks -> linear 16KB global_load_lds staging, conflict-free
// lane-contiguous ds_read_b128.

// K1: normalize rows -> xnbF, per-class column sums (register-accumulated, then
// LDS, then 16-way-split global atomics: chain 32), counts, mask mf, zero-init.
__global__ __launch_bounds__(256) void k_norm(const float* __restrict__ data,
                                              const int* __restrict__ label,
                                              char* __restrict__ xnbF,
                                              float* __restrict__ gh16,
                                              int* __restrict__ cnt16,
                                              float* __restrict__ Zr,
                                              float* __restrict__ Ur,
                                              float* __restrict__ Vr,
                                              float* __restrict__ mf) {
  __shared__ float shg[256];
  __shared__ int shc[2];
  int tid = threadIdx.x, wave = tid >> 6, lane = tid & 63;
  int lh = lane & 31, rsel = lane >> 5;
  if (tid < 2) shc[tid] = 0;
  shg[tid] = 0.f;
  int rowbase = blockIdx.x * 16;
  if (tid < 16) {  // zero this block's accumulator rows (workspace is poisoned)
    int row = rowbase + tid;
    Zr[row] = 0.f; Ur[row] = 0.f; Vr[row] = 0.f;
    mf[row] = (label[row] == 0) ? 1.f : 0.f;
  }
  __syncthreads();

  float a00 = 0.f, a01 = 0.f, a02 = 0.f, a03 = 0.f;  // class-0 column partials
  float a10 = 0.f, a11 = 0.f, a12 = 0.f, a13 = 0.f;  // class-1
  int c0 = 0, c1 = 0;
#pragma unroll
  for (int it = 0; it < 2; ++it) {
    int row = rowbase + it * 8 + wave * 2 + rsel;
    float4 v = *(const float4*)&data[row * DD + lh * 4];  // 16B/lane coalesced
    float ss = v.x * v.x + v.y * v.y + v.z * v.z + v.w * v.w;
#pragma unroll
    for (int off = 16; off; off >>= 1) ss += __shfl_xor(ss, off);  // 32-lane
    float rn = 1.f / fmaxf(sqrtf(ss), 1e-12f);  // F.normalize eps clamp
    float x0 = v.x * rn, x1 = v.y * rn, x2 = v.z * rn, x3 = v.w * rn;

    unsigned pk0 = (unsigned)(unsigned short)f2bf(x0) |
                   ((unsigned)(unsigned short)f2bf(x1) << 16);
    unsigned pk1 = (unsigned)(unsigned short)f2bf(x2) |
                   ((unsigned)(unsigned short)f2bf(x3) << 16);
    int kc = lh >> 1;
    size_t chunk = (size_t)(row >> 4) * 256 + (size_t)(kc >> 2) * 64 +
                   (size_t)(kc & 3) * 16 + (row & 15);
    *(uint2*)(xnbF + chunk * 16 + (lh & 1) * 8) = make_uint2(pk0, pk1);

    int lab = label[row];  // half-wave uniform
    if (lab == 0) {
      a00 += x0; a01 += x1; a02 += x2; a03 += x3;
      if (lh == 0) c0++;
    } else {
      a10 += x0; a11 += x1; a12 += x2; a13 += x3;
      if (lh == 0) c1++;
    }
  }
  int base = lh * 4;
  atomicAdd(&shg[base + 0], a00); atomicAdd(&shg[base + 1], a01);
  atomicAdd(&shg[base + 2], a02); atomicAdd(&shg[base + 3], a03);
  atomicAdd(&shg[128 + base + 0], a10); atomicAdd(&shg[128 + base + 1], a11);
  atomicAdd(&shg[128 + base + 2], a12); atomicAdd(&shg[128 + base + 3], a13);
  if (lh == 0) { atomicAdd(&shc[0], c0); atomicAdd(&shc[1], c1); }
  __syncthreads();
  // 16-way-split targets: per-address global atomic chain is 512/16 = 32
  atomicAdd(&gh16[(blockIdx.x & 15) * 256 + tid], shg[tid]);
  if (tid < 2) atomicAdd(&cnt16[(blockIdx.x & 15) * 2 + tid], shc[tid]);
}

// K3: SYMMETRIC Gram-row reductions (e_ij = e_ji; e*l symmetric too).
// Round-7 post-mortem: launch_bounds(512,4) capped regs at 128 < the ~150 the
// symmetric epilogue needs -> 100MB/dispatch scratch (VGPR=64, WRITE 116MB).
// Fix: 256-thread blocks + launch_bounds(256,3) -> cap ~170 regs, 3 blocks/CU
// (12 waves/CU), LDS 96KB/CU. Triangle refined to 128x128 quadrant jobs over
// NQ=64 row-blocks: 2080 jobs (2080/768 slots = 2.71 passes, ~92% tail util).
// Off-diagonal jobs emit row-sums AND, via in-register column-sums + symmetry,
// the transposed contributions (col-direction V weights by the ROW mask).
// Work = 50.8% of the full matrix. Diagonal jobs emit row-sums only.
__global__ __launch_bounds__(256, 3) void k_main(const short* __restrict__ xnbF,
                                                 const int* __restrict__ label,
                                                 const float* __restrict__ mf,
                                                 const float* __restrict__ scale,
                                                 float* __restrict__ Zr,
                                                 float* __restrict__ Ur,
                                                 float* __restrict__ Vr) {
  __shared__ short tile[2][64 * DD];  // 2 x 16KB double buffer
  int tid = threadIdx.x, wave = tid >> 6, lane = tid & 63;
  int quad = lane >> 4, col = lane & 15;
  // triangular decode over NQ=64 row-blocks of 128
  int qi = 0, rem = blockIdx.x;
  while (rem >= 64 - qi) { rem -= 64 - qi; ++qi; }  // uniform, <=64 iters
  int qj = qi + rem;
  bool offd = (qi != qj);
  float se2 = __expf(scale[0]) * L2E;  // exp(scale)*log2(e): log2-domain logits

  const short8* F = (const short8*)xnbF;  // indexed by 16B chunk

  // A fragments: 2 row-sets of 16 rows (32 rows/wave); scaled by se2 once.
  int gA = qi * 8 + wave * 2;
  short8 af[2][4];
#pragma unroll
  for (int s = 0; s < 2; ++s)
#pragma unroll
    for (int tt = 0; tt < 4; ++tt) {
      short8 a = F[(size_t)(gA + s) * 256 + tt * 64 + lane];
#pragma unroll
      for (int i = 0; i < 8; ++i) a[i] = f2bf(bf2f(a[i]) * se2);
      af[s][tt] = a;
    }

  // row masks (class-0 indicator of this wave's rows) for col-direction V
  int rowb = qi * 128 + wave * 32;
  float mr0[4], mr1[4];
#pragma unroll
  for (int r = 0; r < 4; ++r) {
    mr0[r] = mf[rowb + quad * 4 + r];
    mr1[r] = mf[rowb + 16 + quad * 4 + r];
  }

  float4v Z0 = {0.f,0.f,0.f,0.f}, Z1 = Z0, U0 = Z0, U1 = Z0, V0 = Z0, V1 = Z0;

  int cgb = qj * 8;        // chunk-group base: 128 cols = 8 cgs, 2 tiles of 4
  int jbase = qj * 128;

  // Stage one 64-col tile (16KB = 1024 chunks): 256 thr x 4 x 16B;
  // dst = wave-uniform base + lane*16 (HW requirement for global_load_lds).
#define STAGE(buf, st)                                                         \
  {                                                                            \
    const char* s_ = (const char*)xnbF +                                       \
                     ((size_t)(cgb + (st) * 4) * 256 + tid) * 16;              \
    char* d_ = (char*)tile[buf] + tid * 16;                                    \
    _Pragma("unroll")                                                          \
    for (int p = 0; p < 4; ++p)                                                \
      __builtin_amdgcn_global_load_lds(                                        \
          (const __attribute__((address_space(1))) void*)(uintptr_t)           \
              (s_ + p * 4096),                                                 \
          (__attribute__((address_space(3))) void*)(uintptr_t)(d_ + p * 4096), \
          16, 0, 0);                                                           \
  }

  STAGE(0, 0);
  __syncthreads();  // tile 0 resident

#pragma unroll 1
  for (int st = 0; st < 2; ++st) {
    if (st == 0) STAGE(1, 1);  // in flight over subtile 0's compute
    const short8* T8 = (const short8*)tile[st];
    int jcb = jbase + st * 64;
#pragma unroll
    for (int jo = 0; jo < 4; ++jo) {
      short8 b0 = T8[jo * 256 + lane];
      short8 b1 = T8[jo * 256 + 64 + lane];
      short8 b2 = T8[jo * 256 + 128 + lane];
      short8 b3 = T8[jo * 256 + 192 + lane];
      float m0 = mf[jcb + jo * 16 + col];  // col class-0 mask (per lane)
      float4v c0 = {0.f, 0.f, 0.f, 0.f}, c1 = c0;
      c0 = __builtin_amdgcn_mfma_f32_16x16x32_bf16(af[0][0], b0, c0, 0, 0, 0);
      c1 = __builtin_amdgcn_mfma_f32_16x16x32_bf16(af[1][0], b0, c1, 0, 0, 0);
      c0 = __builtin_amdgcn_mfma_f32_16x16x32_bf16(af[0][1], b1, c0, 0, 0, 0);
      c1 = __builtin_amdgcn_mfma_f32_16x16x32_bf16(af[1][1], b1, c1, 0, 0, 0);
      c0 = __builtin_amdgcn_mfma_f32_16x16x32_bf16(af[0][2], b2, c0, 0, 0, 0);
      c1 = __builtin_amdgcn_mfma_f32_16x16x32_bf16(af[1][2], b2, c1, 0, 0, 0);
      c0 = __builtin_amdgcn_mfma_f32_16x16x32_bf16(af[0][3], b3, c0, 0, 0, 0);
      c1 = __builtin_amdgcn_mfma_f32_16x16x32_bf16(af[1][3], b3, c1, 0, 0, 0);
      float zc = 0.f, uc = 0.f, vc = 0.f;  // column partials (this wave's rows)
#pragma unroll
      for (int r = 0; r < 4; ++r) {  // C/D: col=lane&15, row=quad*4+r (m89)
        float l = c0[r], e = EXP2(l);  // log2-domain, |l|<=20.6: fp32-safe
        Z0[r] += e; U0[r] = fmaf(e, l, U0[r]); V0[r] = fmaf(m0, e, V0[r]);
        zc += e; uc = fmaf(e, l, uc); vc = fmaf(mr0[r], e, vc);
        l = c1[r]; e = EXP2(l);
        Z1[r] += e; U1[r] = fmaf(e, l, U1[r]); V1[r] = fmaf(m0, e, V1[r]);
        zc += e; uc = fmaf(e, l, uc); vc = fmaf(mr1[r], e, vc);
      }
      if (offd) {  // transpose contributions: cols J become rows via symmetry
        zc += __shfl_xor(zc, 16); uc += __shfl_xor(uc, 16);
        vc += __shfl_xor(vc, 16);
        zc += __shfl_xor(zc, 32); uc += __shfl_xor(uc, 32);
        vc += __shfl_xor(vc, 32);
        if (quad == 0) {  // lanes 0..15: one col each
          int jc = jcb + jo * 16 + col;
          atomicAdd(&Zr[jc], zc);
          atomicAdd(&Ur[jc], uc * LN2);  // log2-domain -> nats
          float vcol = (m0 != 0.f) ? vc : (zc - vc);  // same-class sum for j
          atomicAdd(&Vr[jc], vcol);
        }
      }
    }
    __syncthreads();  // st=0: drains STAGE(1); st=1: harmless
  }
#undef STAGE

  // row-direction: reduce across the 16 column-lanes sharing each output row
#define EMIT(s, Zc, Uc, Vc)                                                    \
  {                                                                            \
    _Pragma("unroll")                                                          \
    for (int r = 0; r < 4; ++r) {                                              \
      float z = Zc[r], u = Uc[r], v0 = Vc[r];                                  \
      _Pragma("unroll")                                                        \
      for (int off = 1; off < 16; off <<= 1) {                                 \
        z += __shfl_xor(z, off);                                               \
        u += __shfl_xor(u, off);                                               \
        v0 += __shfl_xor(v0, off);                                             \
      }                                                                        \
      if (col == 0) {                                                          \
        int row = rowb + s * 16 + quad * 4 + r;                                \
        int lab = label[row];                                                  \
        float v = (lab == 0) ? v0 : (z - v0);                                  \
        atomicAdd(&Zr[row], z);                                                \
        atomicAdd(&Ur[row], u * LN2); /* log2-domain -> nats */                \
        atomicAdd(&Vr[row], v);                                                \
      }                                                                        \
    }                                                                          \
  }
  EMIT(0, Z0, U0, V0)
  EMIT(1, Z1, U1, V1)
#undef EMIT
}

// K4: per-row loss; S,T via closed-form dots with class sums. 512 blocks x 16
// rows; per-block partial + agent-scope last-block ticket does the final sum.
__global__ __launch_bounds__(256) void k_final(const float* __restrict__ data,
                                               const int* __restrict__ label,
                                               const float* __restrict__ scale,
                                               const float* __restrict__ gh16,
                                               const int* __restrict__ cnt16,
                                               const float* __restrict__ Zr,
                                               const float* __restrict__ Ur,
                                               const float* __restrict__ Vr,
                                               float* __restrict__ partial,
                                               int* __restrict__ ticket,
                                               float* __restrict__ out) {
  __shared__ float hsum[256];
  __shared__ float bsum[4];
  __shared__ int lastb;
  int tid = threadIdx.x, wave = tid >> 6, lane = tid & 63;
  int lh = lane & 31, rsel = lane >> 5;
  float hs = 0.f;
#pragma unroll
  for (int i = 0; i < 16; ++i) hs += gh16[i * 256 + tid];
  hsum[tid] = hs;
  __syncthreads();

  float se = __expf(scale[0]);
  int ci0 = 0, ci1 = 0;
#pragma unroll
  for (int i = 0; i < 16; ++i) { ci0 += cnt16[2 * i]; ci1 += cnt16[2 * i + 1]; }
  float c0 = (float)ci0, c1 = (float)ci1;
  float4 h0 = *(const float4*)&hsum[lh * 4];
  float4 h1 = *(const float4*)&hsum[128 + lh * 4];

  float local = 0.f;
#pragma unroll
  for (int it = 0; it < 2; ++it) {
    int row = blockIdx.x * 16 + it * 8 + wave * 2 + rsel;
    float4 v = *(const float4*)&data[row * DD + lh * 4];
    float ss = v.x * v.x + v.y * v.y + v.z * v.z + v.w * v.w;
#pragma unroll
    for (int off = 16; off; off >>= 1) ss += __shfl_xor(ss, off);
    float rn = 1.f / fmaxf(sqrtf(ss), 1e-12f);

    int lab = label[row];
    float sg = v.x * (h0.x + h1.x) + v.y * (h0.y + h1.y) +
               v.z * (h0.z + h1.z) + v.w * (h0.w + h1.w);
    float sh_ = (lab == 0)
                    ? (v.x * h0.x + v.y * h0.y + v.z * h0.z + v.w * h0.w)
                    : (v.x * h1.x + v.y * h1.y + v.z * h1.z + v.w * h1.w);
#pragma unroll
    for (int off = 16; off; off >>= 1) {
      sg += __shfl_xor(sg, off);
      sh_ += __shfl_xor(sh_, off);
    }
    if (lh == 0) {
      float cc = (lab == 0) ? c0 : c1;
      float a = __expf(1.f / cc);
      float Zq = cc * a + ((float)BS - cc);
      float S = se * sg * rn, T = se * sh_ * rn;
      float Zv = Zr[row], Uv = Ur[row], Vv = Vr[row];
      // loss_i = a/Zq - (S+(a-1)T)/Zq + U/Z - V/(c*Z)  (M_i, log Zq cancelled)
      local += a / Zq - (S + (a - 1.f) * T) / Zq + Uv / Zv - Vv / (cc * Zv);
    }
  }
  // local is nonzero only on lanes 0 and 32; full-wave reduce is safe
#pragma unroll
  for (int off = 32; off; off >>= 1) local += __shfl_xor(local, off);
  if (lane == 0) bsum[wave] = local;
  __syncthreads();
  if (tid == 0) {
    float psum = bsum[0] + bsum[1] + bsum[2] + bsum[3];
    __hip_atomic_store(&partial[blockIdx.x], psum, __ATOMIC_RELEASE,
                       __HIP_MEMORY_SCOPE_AGENT);
    int t = __hip_atomic_fetch_add(ticket, 1, __ATOMIC_ACQ_REL,
                                   __HIP_MEMORY_SCOPE_AGENT);
    lastb = (t == 511);
  }
  __syncthreads();
  if (lastb) {  // last block sums all 512 partials and stores the result
    float v = __hip_atomic_load(&partial[tid], __ATOMIC_ACQUIRE,
                                __HIP_MEMORY_SCOPE_AGENT) +
              __hip_atomic_load(&partial[tid + 256], __ATOMIC_ACQUIRE,
                                __HIP_MEMORY_SCOPE_AGENT);
#pragma unroll
    for (int off = 32; off; off >>= 1) v += __shfl_xor(v, off);
    if (lane == 0) bsum[wave] = v;
    __syncthreads();
    if (tid == 0)
      out[0] = (bsum[0] + bsum[1] + bsum[2] + bsum[3]) * (0.5f / (float)BS);
  }
}

extern "C" void kernel_launch(void* const* d_in, const int* in_sizes, int n_in,
                              void* d_out, int out_size, void* d_ws, size_t ws_size,
                              hipStream_t stream) {
  const float* data = (const float*)d_in[0];
  const float* scale = (const float*)d_in[1];
  const int* label = (const int*)d_in[2];
  char* ws = (char*)d_ws;
  // ws layout (bytes):
  //   0        xnbF bf16 fragment-order [8192*128]   2 MB
  //   2097152  Zr      f32 [8192]
  //   2129920  Ur      f32 [8192]
  //   2162688  Vr      f32 [8192]
  //   2195456  gh16    f32 [16][256]  (16-way split class sums)
  //   2211840  cnt16   int [32]       (16-way split class counts)
  //   2211968  ticket  int [1]
  //   2211972  partial f32 [512]
  //   2214020  mf      f32 [8192]
  char* xnbF = ws;
  float* Zr = (float*)(ws + 2097152);
  float* Ur = (float*)(ws + 2129920);
  float* Vr = (float*)(ws + 2162688);
  float* gh16 = (float*)(ws + 2195456);
  int* cnt16 = (int*)(ws + 2211840);
  int* ticket = (int*)(ws + 2211968);
  float* partial = (float*)(ws + 2211972);
  float* mf = (float*)(ws + 2214020);

  // gh16+cnt16+ticket (16516 B); Zr/Ur/Vr/mf zeroed in k_norm; partial fully
  // written by k_final before any read; out stored by k_final's last block.
  hipMemsetAsync(ws + 2195456, 0, 16516, stream);

  k_norm<<<512, 256, 0, stream>>>(data, label, xnbF, gh16, cnt16, Zr, Ur, Vr, mf);
  k_main<<<2080, 256, 0, stream>>>((const short*)xnbF, label, mf, scale, Zr, Ur, Vr);
  k_final<<<512, 256, 0, stream>>>(data, label, scale, gh16, cnt16, Zr, Ur, Vr,
                                   partial, ticket, (float*)d_out);
}

// Round 11
// 117.107 us; speedup vs baseline: 1.3857x; 1.2861x over previous
//
#include <hip/hip_runtime.h>
#include <stdint.h>

#define BS 8192
#define DD 128
#define L2E 1.4426950408889634f
#define LN2 0.6931471805599453f

typedef __attribute__((ext_vector_type(8))) short short8;
typedef __attribute__((ext_vector_type(4))) float float4v;

#if __has_builtin(__builtin_amdgcn_exp2f)
#define EXP2(x) __builtin_amdgcn_exp2f(x)
#else
#define EXP2(x) exp2f(x)
#endif

__device__ __forceinline__ float bf2f(short s) {
  union { unsigned u; float f; } c;
  c.u = ((unsigned)(unsigned short)s) << 16;
  return c.f;
}
__device__ __forceinline__ short f2bf(float f) {
  union { float f; unsigned u; } c; c.f = f;
  unsigned u = c.u + 0x7FFFu + ((c.u >> 16) & 1u);
  return (short)(u >> 16);
}

// Fragment-ordered bf16 layout ("xnbF"): 16-byte chunk index for (row, kc):
//   chunk(row,kc) = (row>>4)*256 + (kc>>2)*64 + (kc&3)*16 + (row&15)
// A wave load F[g*256 + t*64 + lane] gives lane (quad=lane>>4, col=lane&15) the
// 8 bf16 of row g*16+col, k-chunk 4t+quad — the verified mfma_f32_16x16x32_bf16
// A/B fragment layout (rounds 2-8 absmax=0). A 64-col panel is 1024 CONTIGUOUS
// chunks -> linear 16KB global_load_lds staging, conflict-free ds_read_b128.
//
// R9/R10 post-mortem: single cooperative kernel FAILED (absmax 7.06) — plain
// stores from phase 1 sat dirty in producer XCDs' L2; grid.sync() fences did
// not make them visible cross-XCD (kernel boundaries do — hence the 3-kernel
// version's absmax 0). Cooperative fusion abandoned. Instead, k_final is
// eliminated ALGEBRAICALLY: Zq/a/c take only 2 per-class values, so the loss
// needs just per-row W=Σl, X=Σ_{j∈class0} l from the Gram pass (cheap epilogue
// adds) + a last-block ticket finale (all producer writes are device-scope
// atomics -> coherence-point-visible; the R5/R6-verified pattern).

// K1: pure streaming: normalize rows -> xnbF; zero accumulators; mask mf.
// No class sums, no LDS, no atomics. 512 blocks x 16 rows.
__global__ __launch_bounds__(256) void k_norm(const float* __restrict__ data,
                                              const int* __restrict__ label,
                                              char* __restrict__ xnbF,
                                              float* __restrict__ Zr,
                                              float* __restrict__ Ur,
                                              float* __restrict__ Vr,
                                              float* __restrict__ Wr,
                                              float* __restrict__ Xr,
                                              float* __restrict__ mf) {
  int tid = threadIdx.x, wave = tid >> 6, lane = tid & 63;
  int lh = lane & 31, rsel = lane >> 5;
  int rowbase = blockIdx.x * 16;
  if (tid < 16) {  // zero this block's accumulator rows (workspace is poisoned)
    int row = rowbase + tid;
    Zr[row] = 0.f; Ur[row] = 0.f; Vr[row] = 0.f; Wr[row] = 0.f; Xr[row] = 0.f;
    mf[row] = (label[row] == 0) ? 1.f : 0.f;
  }
#pragma unroll
  for (int it = 0; it < 2; ++it) {
    int row = rowbase + it * 8 + wave * 2 + rsel;
    float4 v = *(const float4*)&data[row * DD + lh * 4];  // 16B/lane coalesced
    float ss = v.x * v.x + v.y * v.y + v.z * v.z + v.w * v.w;
#pragma unroll
    for (int off = 16; off; off >>= 1) ss += __shfl_xor(ss, off);  // 32-lane
    float rn = 1.f / fmaxf(sqrtf(ss), 1e-12f);  // F.normalize eps clamp
    float x0 = v.x * rn, x1 = v.y * rn, x2 = v.z * rn, x3 = v.w * rn;

    unsigned pk0 = (unsigned)(unsigned short)f2bf(x0) |
                   ((unsigned)(unsigned short)f2bf(x1) << 16);
    unsigned pk1 = (unsigned)(unsigned short)f2bf(x2) |
                   ((unsigned)(unsigned short)f2bf(x3) << 16);
    int kc = lh >> 1;
    size_t chunk = (size_t)(row >> 4) * 256 + (size_t)(kc >> 2) * 64 +
                   (size_t)(kc & 3) * 16 + (row & 15);
    *(uint2*)(xnbF + chunk * 16 + (lh & 1) * 8) = make_uint2(pk0, pk1);
  }
}

// K2: full-matrix Gram-row reductions (R6 body) + W/X epilogue + ticket finale.
// Per logit (log2-domain l, e=2^l): Z+=e, U+=e*l, V+=m*e, W+=l, X+=m*l.
// Per row emitted: Z, U*ln2, V(class-matched), W*ln2 (=S_i in nats, se folded
// in), X*ln2 (=T_i). Last block (ticket==511) computes counts + total loss.
__global__ __launch_bounds__(512, 4) void k_main(const short* __restrict__ xnbF,
                                                 const int* __restrict__ label,
                                                 const float* __restrict__ mf,
                                                 const float* __restrict__ scale,
                                                 float* __restrict__ Zr,
                                                 float* __restrict__ Ur,
                                                 float* __restrict__ Vr,
                                                 float* __restrict__ Wr,
                                                 float* __restrict__ Xr,
                                                 int* __restrict__ ticket,
                                                 float* __restrict__ out) {
  __shared__ short tile[2][64 * DD];  // 2 x 16KB double buffer
  __shared__ int credu[8];
  __shared__ float fredu[8];
  __shared__ int lastf;
  int tid = threadIdx.x, wave = tid >> 6, lane = tid & 63;
  int quad = lane >> 4, col = lane & 15;
  int rbI = blockIdx.x >> 4;  // 0..31: 256-row block (8 waves x 32 rows)
  int sl = blockIdx.x & 15;   // 0..15: 512-col slice (8 tiles of 64)
  float se2 = __expf(scale[0]) * L2E;  // exp(scale)*log2(e): log2-domain logits

  const short8* F = (const short8*)xnbF;
  int gA = rbI * 16 + wave * 2;
  short8 af[2][4];
#pragma unroll
  for (int s = 0; s < 2; ++s)
#pragma unroll
    for (int t = 0; t < 4; ++t) {
      short8 a = F[(size_t)(gA + s) * 256 + t * 64 + lane];
#pragma unroll
      for (int i = 0; i < 8; ++i) a[i] = f2bf(bf2f(a[i]) * se2);
      af[s][t] = a;
    }

  float4v Z0 = {0.f,0.f,0.f,0.f}, Z1 = Z0, U0 = Z0, U1 = Z0, V0 = Z0, V1 = Z0;
  float4v W0 = Z0, W1 = Z0, X0 = Z0, X1 = Z0;
  int cb4 = sl * 32;  // chunk-group base of this slice

#define STAGE(buf, jt)                                                         \
  {                                                                            \
    const char* s_ = (const char*)xnbF +                                       \
                     ((size_t)(cb4 + (jt) * 4) * 256 + tid) * 16;              \
    char* d_ = (char*)tile[buf] + tid * 16;                                    \
    __builtin_amdgcn_global_load_lds(                                          \
        (const __attribute__((address_space(1))) void*)(uintptr_t)s_,          \
        (__attribute__((address_space(3))) void*)(uintptr_t)d_, 16, 0, 0);     \
    __builtin_amdgcn_global_load_lds(                                          \
        (const __attribute__((address_space(1))) void*)(uintptr_t)(s_ + 8192), \
        (__attribute__((address_space(3))) void*)(uintptr_t)(d_ + 8192),       \
        16, 0, 0);                                                             \
  }

  STAGE(0, 0);
  __syncthreads();  // tile 0 resident

#pragma unroll 1
  for (int jt = 0; jt < 8; ++jt) {
    if (jt < 7) STAGE((jt + 1) & 1, jt + 1);  // in flight over this compute
    const short8* T8 = (const short8*)tile[jt & 1];
    int jcb = sl * 512 + jt * 64;

#define HALFTILE(jo)                                                           \
    {                                                                          \
      short8 b00 = T8[(jo) * 256 + lane];                                      \
      short8 b01 = T8[(jo) * 256 + 64 + lane];                                 \
      short8 b02 = T8[(jo) * 256 + 128 + lane];                                \
      short8 b03 = T8[(jo) * 256 + 192 + lane];                                \
      short8 b10 = T8[(jo + 1) * 256 + lane];                                  \
      short8 b11 = T8[(jo + 1) * 256 + 64 + lane];                             \
      short8 b12 = T8[(jo + 1) * 256 + 128 + lane];                            \
      short8 b13 = T8[(jo + 1) * 256 + 192 + lane];                            \
      float m0 = mf[jcb + (jo) * 16 + col];                                    \
      float m1 = mf[jcb + (jo + 1) * 16 + col];                                \
      float4v c00 = {0.f, 0.f, 0.f, 0.f}, c01 = c00, c10 = c00, c11 = c00;     \
      c00 = __builtin_amdgcn_mfma_f32_16x16x32_bf16(af[0][0], b00, c00, 0,0,0);\
      c01 = __builtin_amdgcn_mfma_f32_16x16x32_bf16(af[1][0], b00, c01, 0,0,0);\
      c10 = __builtin_amdgcn_mfma_f32_16x16x32_bf16(af[0][0], b10, c10, 0,0,0);\
      c11 = __builtin_amdgcn_mfma_f32_16x16x32_bf16(af[1][0], b10, c11, 0,0,0);\
      c00 = __builtin_amdgcn_mfma_f32_16x16x32_bf16(af[0][1], b01, c00, 0,0,0);\
      c01 = __builtin_amdgcn_mfma_f32_16x16x32_bf16(af[1][1], b01, c01, 0,0,0);\
      c10 = __builtin_amdgcn_mfma_f32_16x16x32_bf16(af[0][1], b11, c10, 0,0,0);\
      c11 = __builtin_amdgcn_mfma_f32_16x16x32_bf16(af[1][1], b11, c11, 0,0,0);\
      c00 = __builtin_amdgcn_mfma_f32_16x16x32_bf16(af[0][2], b02, c00, 0,0,0);\
      c01 = __builtin_amdgcn_mfma_f32_16x16x32_bf16(af[1][2], b02, c01, 0,0,0);\
      c10 = __builtin_amdgcn_mfma_f32_16x16x32_bf16(af[0][2], b12, c10, 0,0,0);\
      c11 = __builtin_amdgcn_mfma_f32_16x16x32_bf16(af[1][2], b12, c11, 0,0,0);\
      c00 = __builtin_amdgcn_mfma_f32_16x16x32_bf16(af[0][3], b03, c00, 0,0,0);\
      c01 = __builtin_amdgcn_mfma_f32_16x16x32_bf16(af[1][3], b03, c01, 0,0,0);\
      c10 = __builtin_amdgcn_mfma_f32_16x16x32_bf16(af[0][3], b13, c10, 0,0,0);\
      c11 = __builtin_amdgcn_mfma_f32_16x16x32_bf16(af[1][3], b13, c11, 0,0,0);\
      _Pragma("unroll")                                                        \
      for (int r = 0; r < 4; ++r) { /* C/D: col=lane&15, row=quad*4+r (m89) */ \
        float l, e;                                                            \
        l = c00[r]; e = EXP2(l);  /* log2-domain, |l|<=20.6: fp32-safe */      \
        Z0[r] += e; U0[r] = fmaf(e, l, U0[r]); V0[r] = fmaf(m0, e, V0[r]);     \
        W0[r] += l; X0[r] = fmaf(m0, l, X0[r]);                                \
        l = c01[r]; e = EXP2(l);                                               \
        Z1[r] += e; U1[r] = fmaf(e, l, U1[r]); V1[r] = fmaf(m0, e, V1[r]);     \
        W1[r] += l; X1[r] = fmaf(m0, l, X1[r]);                                \
        l = c10[r]; e = EXP2(l);                                               \
        Z0[r] += e; U0[r] = fmaf(e, l, U0[r]); V0[r] = fmaf(m1, e, V0[r]);     \
        W0[r] += l; X0[r] = fmaf(m1, l, X0[r]);                                \
        l = c11[r]; e = EXP2(l);                                               \
        Z1[r] += e; U1[r] = fmaf(e, l, U1[r]); V1[r] = fmaf(m1, e, V1[r]);     \
        W1[r] += l; X1[r] = fmaf(m1, l, X1[r]);                                \
      }                                                                        \
    }
    HALFTILE(0)
    HALFTILE(2)
#undef HALFTILE
    __syncthreads();  // drains stage(jt+1); protects overwritten buffer
  }
#undef STAGE

  // reduce across the 16 column-lanes sharing each output row, then atomics
#define EMIT(s, Zc, Uc, Vc, Wc, Xc)                                            \
  {                                                                            \
    _Pragma("unroll")                                                          \
    for (int r = 0; r < 4; ++r) {                                              \
      float z = Zc[r], u = Uc[r], v0 = Vc[r], w = Wc[r], x0 = Xc[r];           \
      _Pragma("unroll")                                                        \
      for (int off = 1; off < 16; off <<= 1) {                                 \
        z += __shfl_xor(z, off);                                               \
        u += __shfl_xor(u, off);                                               \
        v0 += __shfl_xor(v0, off);                                             \
        w += __shfl_xor(w, off);                                               \
        x0 += __shfl_xor(x0, off);                                             \
      }                                                                        \
      if (col == 0) {                                                          \
        int row = rbI * 256 + wave * 32 + s * 16 + quad * 4 + r;               \
        int lab = label[row];                                                  \
        float v = (lab == 0) ? v0 : (z - v0);                                  \
        float x = (lab == 0) ? x0 : (w - x0);                                  \
        atomicAdd(&Zr[row], z);                                                \
        atomicAdd(&Ur[row], u * LN2); /* log2-domain -> nats */                \
        atomicAdd(&Vr[row], v);                                                \
        atomicAdd(&Wr[row], w * LN2); /* S_i in nats (se folded in l) */       \
        atomicAdd(&Xr[row], x * LN2); /* T_i in nats */                        \
      }                                                                        \
    }                                                                          \
  }
  EMIT(0, Z0, U0, V0, W0, X0)
  EMIT(1, Z1, U1, V1, W1, X1)
#undef EMIT

  // ---- ticket finale: last block computes counts + total loss in-kernel ----
  __syncthreads();  // drains every wave's EMIT atomics (vmcnt 0 before barrier)
  if (tid == 0) {
    int t = __hip_atomic_fetch_add(ticket, 1, __ATOMIC_ACQ_REL,
                                   __HIP_MEMORY_SCOPE_AGENT);
    lastf = (t == 511);
  }
  __syncthreads();
  if (!lastf) return;

  // All 512 blocks' device-scope atomics are at the coherence point.
  int labs[16];
  int c1i = 0;
#pragma unroll
  for (int k = 0; k < 16; ++k) {
    labs[k] = label[k * 512 + tid];  // coalesced; labels in {0,1}
    c1i += labs[k];
  }
#pragma unroll
  for (int off = 32; off; off >>= 1) c1i += __shfl_xor(c1i, off);
  if (lane == 0) credu[wave] = c1i;
  __syncthreads();
  int c1t = 0;
#pragma unroll
  for (int w = 0; w < 8; ++w) c1t += credu[w];
  float c1 = (float)c1t, c0 = (float)(BS - c1t);
  float a0 = __expf(1.f / c0), a1 = __expf(1.f / c1);
  float rZq0 = 1.f / (c0 * a0 + ((float)BS - c0));
  float rZq1 = 1.f / (c1 * a1 + ((float)BS - c1));
  float rc0 = 1.f / c0, rc1 = 1.f / c1;

  float local = 0.f;
#pragma unroll
  for (int k = 0; k < 16; ++k) {
    int row = k * 512 + tid;
    float Z = __hip_atomic_load(&Zr[row], __ATOMIC_RELAXED, __HIP_MEMORY_SCOPE_AGENT);
    float U = __hip_atomic_load(&Ur[row], __ATOMIC_RELAXED, __HIP_MEMORY_SCOPE_AGENT);
    float V = __hip_atomic_load(&Vr[row], __ATOMIC_RELAXED, __HIP_MEMORY_SCOPE_AGENT);
    float S = __hip_atomic_load(&Wr[row], __ATOMIC_RELAXED, __HIP_MEMORY_SCOPE_AGENT);
    float T = __hip_atomic_load(&Xr[row], __ATOMIC_RELAXED, __HIP_MEMORY_SCOPE_AGENT);
    int lab = labs[k];
    float a = lab ? a1 : a0;
    float rZq = lab ? rZq1 : rZq0;
    float rc = lab ? rc1 : rc0;
    // loss_i = a/Zq - (S + (a-1)T)/Zq + U/Z - V/(c*Z)  (M_i, log Zq cancelled)
    local += rZq * (a - S - (a - 1.f) * T) + (U - V * rc) / Z;
  }
#pragma unroll
  for (int off = 32; off; off >>= 1) local += __shfl_xor(local, off);
  if (lane == 0) fredu[wave] = local;
  __syncthreads();
  if (tid == 0) {
    float s = 0.f;
#pragma unroll
    for (int w = 0; w < 8; ++w) s += fredu[w];
    out[0] = s * (0.5f / (float)BS);
  }
}

extern "C" void kernel_launch(void* const* d_in, const int* in_sizes, int n_in,
                              void* d_out, int out_size, void* d_ws, size_t ws_size,
                              hipStream_t stream) {
  const float* data = (const float*)d_in[0];
  const float* scale = (const float*)d_in[1];
  const int* label = (const int*)d_in[2];
  char* ws = (char*)d_ws;
  // ws layout (bytes):
  //   0        xnbF bf16 fragment-order [8192*128]   2 MB
  //   2097152  Zr     f32 [8192]
  //   2129920  Ur     f32 [8192]
  //   2162688  Vr     f32 [8192]
  //   2195456  Wr     f32 [8192]   (per-row logit sum S_i, nats)
  //   2228224  Xr     f32 [8192]   (per-row same-class logit sum T_i, nats)
  //   2260992  mf     f32 [8192]
  //   2293760  ticket int [1]
  char* xnbF = ws;
  float* Zr = (float*)(ws + 2097152);
  float* Ur = (float*)(ws + 2129920);
  float* Vr = (float*)(ws + 2162688);
  float* Wr = (float*)(ws + 2195456);
  float* Xr = (float*)(ws + 2228224);
  float* mf = (float*)(ws + 2260992);
  int* ticket = (int*)(ws + 2293760);

  // ticket only (4 B); Zr/Ur/Vr/Wr/Xr/mf zeroed in k_norm; out stored by
  // k_main's last block (harness also pre-zeroes out).
  hipMemsetAsync(ws + 2293760, 0, 4, stream);

  k_norm<<<512, 256, 0, stream>>>(data, label, xnbF, Zr, Ur, Vr, Wr, Xr, mf);
  k_main<<<512, 512, 0, stream>>>((const short*)xnbF, label, mf, scale, Zr, Ur,
                                  Vr, Wr, Xr, ticket, (float*)d_out);
}

// Round 12
// 102.906 us; speedup vs baseline: 1.5769x; 1.1380x over previous
//
#include <hip/hip_runtime.h>
#include <stdint.h>

#define BS 8192
#define DD 128
#define L2E 1.4426950408889634f
#define LN2 0.6931471805599453f

typedef __attribute__((ext_vector_type(8))) short short8;
typedef __attribute__((ext_vector_type(4))) float float4v;

#if __has_builtin(__builtin_amdgcn_exp2f)
#define EXP2(x) __builtin_amdgcn_exp2f(x)
#else
#define EXP2(x) exp2f(x)
#endif

__device__ __forceinline__ float bf2f(short s) {
  union { unsigned u; float f; } c;
  c.u = ((unsigned)(unsigned short)s) << 16;
  return c.f;
}
__device__ __forceinline__ short f2bf(float f) {
  union { float f; unsigned u; } c; c.f = f;
  unsigned u = c.u + 0x7FFFu + ((c.u >> 16) & 1u);
  return (short)(u >> 16);
}

// Fragment-ordered bf16 layout ("xnbF"): 16-byte chunk index for (row, kc):
//   chunk(row,kc) = (row>>4)*256 + (kc>>2)*64 + (kc&3)*16 + (row&15)
// A wave load F[g*256 + t*64 + lane] gives lane (quad=lane>>4, col=lane&15) the
// 8 bf16 of row g*16+col, k-chunk 4t+quad — the verified mfma_f32_16x16x32_bf16
// A/B fragment layout (rounds 2-11 absmax=0). A 64-col panel is 1024 CONTIGUOUS
// chunks -> linear 16KB global_load_lds staging, conflict-free ds_read_b128.
//
// R11 post-mortem: per-row W/X accumulators in the hot loop re-spilled (VGPR
// 64, +12MB scratch traffic, 61.5us). Fix is ALGEBRA: S,T are rank-1, so their
// class-summed loss contribution collapses to 3 dot products of the 128-dim
// class-sum vectors h0,h1 (se*h0.g, se*h0.h0, ...). Hot loop reverts to the
// EXACT R6 body (Z/U/V only, VGPR 80 verified no-spill); h0/h1 come from
// k_norm's 16-way-split atomics; the ticket finale does counts + 3 dots +
// per-row (U-V/c)/Z in cold-path code.

// K1: normalize rows -> xnbF; class column sums -> gh16 (16-way split, chain
// 32); zero accumulators; mask mf. 512 blocks x 16 rows.
__global__ __launch_bounds__(256) void k_norm(const float* __restrict__ data,
                                              const int* __restrict__ label,
                                              char* __restrict__ xnbF,
                                              float* __restrict__ gh16,
                                              float* __restrict__ Zr,
                                              float* __restrict__ Ur,
                                              float* __restrict__ Vr,
                                              float* __restrict__ mf) {
  __shared__ float shg[256];
  int tid = threadIdx.x, wave = tid >> 6, lane = tid & 63;
  int lh = lane & 31, rsel = lane >> 5;
  shg[tid] = 0.f;
  int rowbase = blockIdx.x * 16;
  if (tid < 16) {  // zero this block's accumulator rows (workspace is poisoned)
    int row = rowbase + tid;
    Zr[row] = 0.f; Ur[row] = 0.f; Vr[row] = 0.f;
    mf[row] = (label[row] == 0) ? 1.f : 0.f;
  }
  __syncthreads();

  float a00 = 0.f, a01 = 0.f, a02 = 0.f, a03 = 0.f;  // class-0 column partials
  float a10 = 0.f, a11 = 0.f, a12 = 0.f, a13 = 0.f;  // class-1
#pragma unroll
  for (int it = 0; it < 2; ++it) {
    int row = rowbase + it * 8 + wave * 2 + rsel;
    float4 v = *(const float4*)&data[row * DD + lh * 4];  // 16B/lane coalesced
    float ss = v.x * v.x + v.y * v.y + v.z * v.z + v.w * v.w;
#pragma unroll
    for (int off = 16; off; off >>= 1) ss += __shfl_xor(ss, off);  // 32-lane
    float rn = 1.f / fmaxf(sqrtf(ss), 1e-12f);  // F.normalize eps clamp
    float x0 = v.x * rn, x1 = v.y * rn, x2 = v.z * rn, x3 = v.w * rn;

    unsigned pk0 = (unsigned)(unsigned short)f2bf(x0) |
                   ((unsigned)(unsigned short)f2bf(x1) << 16);
    unsigned pk1 = (unsigned)(unsigned short)f2bf(x2) |
                   ((unsigned)(unsigned short)f2bf(x3) << 16);
    int kc = lh >> 1;
    size_t chunk = (size_t)(row >> 4) * 256 + (size_t)(kc >> 2) * 64 +
                   (size_t)(kc & 3) * 16 + (row & 15);
    *(uint2*)(xnbF + chunk * 16 + (lh & 1) * 8) = make_uint2(pk0, pk1);

    int lab = label[row];  // half-wave uniform
    if (lab == 0) {
      a00 += x0; a01 += x1; a02 += x2; a03 += x3;
    } else {
      a10 += x0; a11 += x1; a12 += x2; a13 += x3;
    }
  }
  int base = lh * 4;  // 8 colliders per LDS address
  atomicAdd(&shg[base + 0], a00); atomicAdd(&shg[base + 1], a01);
  atomicAdd(&shg[base + 2], a02); atomicAdd(&shg[base + 3], a03);
  atomicAdd(&shg[128 + base + 0], a10); atomicAdd(&shg[128 + base + 1], a11);
  atomicAdd(&shg[128 + base + 2], a12); atomicAdd(&shg[128 + base + 3], a13);
  __syncthreads();
  // 16-way-split targets: per-address global atomic chain is 512/16 = 32
  atomicAdd(&gh16[(blockIdx.x & 15) * 256 + tid], shg[tid]);
}

// K2: full-matrix Gram-row reductions (EXACT R6 hot loop) + ticket finale.
__global__ __launch_bounds__(512, 4) void k_main(const short* __restrict__ xnbF,
                                                 const int* __restrict__ label,
                                                 const float* __restrict__ mf,
                                                 const float* __restrict__ scale,
                                                 const float* __restrict__ gh16,
                                                 float* __restrict__ Zr,
                                                 float* __restrict__ Ur,
                                                 float* __restrict__ Vr,
                                                 int* __restrict__ ticket,
                                                 float* __restrict__ out) {
  __shared__ short tile[2][64 * DD];  // 2 x 16KB double buffer
  __shared__ int credu[8];
  __shared__ float fredu[8];
  __shared__ float dred[24];  // 3 dot partials x 8 waves
  __shared__ int lastf;
  int tid = threadIdx.x, wave = tid >> 6, lane = tid & 63;
  int quad = lane >> 4, col = lane & 15;
  int rbI = blockIdx.x >> 4;  // 0..31: 256-row block (8 waves x 32 rows)
  int sl = blockIdx.x & 15;   // 0..15: 512-col slice (8 tiles of 64)
  float se2 = __expf(scale[0]) * L2E;  // exp(scale)*log2(e): log2-domain logits

  const short8* F = (const short8*)xnbF;
  int gA = rbI * 16 + wave * 2;
  short8 af[2][4];
#pragma unroll
  for (int s = 0; s < 2; ++s)
#pragma unroll
    for (int t = 0; t < 4; ++t) {
      short8 a = F[(size_t)(gA + s) * 256 + t * 64 + lane];
#pragma unroll
      for (int i = 0; i < 8; ++i) a[i] = f2bf(bf2f(a[i]) * se2);
      af[s][t] = a;
    }

  float4v Z0 = {0.f,0.f,0.f,0.f}, Z1 = Z0, U0 = Z0, U1 = Z0, V0 = Z0, V1 = Z0;
  int cb4 = sl * 32;  // chunk-group base of this slice

#define STAGE(buf, jt)                                                         \
  {                                                                            \
    const char* s_ = (const char*)xnbF +                                       \
                     ((size_t)(cb4 + (jt) * 4) * 256 + tid) * 16;              \
    char* d_ = (char*)tile[buf] + tid * 16;                                    \
    __builtin_amdgcn_global_load_lds(                                          \
        (const __attribute__((address_space(1))) void*)(uintptr_t)s_,          \
        (__attribute__((address_space(3))) void*)(uintptr_t)d_, 16, 0, 0);     \
    __builtin_amdgcn_global_load_lds(                                          \
        (const __attribute__((address_space(1))) void*)(uintptr_t)(s_ + 8192), \
        (__attribute__((address_space(3))) void*)(uintptr_t)(d_ + 8192),       \
        16, 0, 0);                                                             \
  }

  STAGE(0, 0);
  __syncthreads();  // tile 0 resident

#pragma unroll 1
  for (int jt = 0; jt < 8; ++jt) {
    if (jt < 7) STAGE((jt + 1) & 1, jt + 1);  // in flight over this compute
    const short8* T8 = (const short8*)tile[jt & 1];
    int jcb = sl * 512 + jt * 64;

#define HALFTILE(jo)                                                           \
    {                                                                          \
      short8 b00 = T8[(jo) * 256 + lane];                                      \
      short8 b01 = T8[(jo) * 256 + 64 + lane];                                 \
      short8 b02 = T8[(jo) * 256 + 128 + lane];                                \
      short8 b03 = T8[(jo) * 256 + 192 + lane];                                \
      short8 b10 = T8[(jo + 1) * 256 + lane];                                  \
      short8 b11 = T8[(jo + 1) * 256 + 64 + lane];                             \
      short8 b12 = T8[(jo + 1) * 256 + 128 + lane];                            \
      short8 b13 = T8[(jo + 1) * 256 + 192 + lane];                            \
      float m0 = mf[jcb + (jo) * 16 + col];                                    \
      float m1 = mf[jcb + (jo + 1) * 16 + col];                                \
      float4v c00 = {0.f, 0.f, 0.f, 0.f}, c01 = c00, c10 = c00, c11 = c00;     \
      c00 = __builtin_amdgcn_mfma_f32_16x16x32_bf16(af[0][0], b00, c00, 0,0,0);\
      c01 = __builtin_amdgcn_mfma_f32_16x16x32_bf16(af[1][0], b00, c01, 0,0,0);\
      c10 = __builtin_amdgcn_mfma_f32_16x16x32_bf16(af[0][0], b10, c10, 0,0,0);\
      c11 = __builtin_amdgcn_mfma_f32_16x16x32_bf16(af[1][0], b10, c11, 0,0,0);\
      c00 = __builtin_amdgcn_mfma_f32_16x16x32_bf16(af[0][1], b01, c00, 0,0,0);\
      c01 = __builtin_amdgcn_mfma_f32_16x16x32_bf16(af[1][1], b01, c01, 0,0,0);\
      c10 = __builtin_amdgcn_mfma_f32_16x16x32_bf16(af[0][1], b11, c10, 0,0,0);\
      c11 = __builtin_amdgcn_mfma_f32_16x16x32_bf16(af[1][1], b11, c11, 0,0,0);\
      c00 = __builtin_amdgcn_mfma_f32_16x16x32_bf16(af[0][2], b02, c00, 0,0,0);\
      c01 = __builtin_amdgcn_mfma_f32_16x16x32_bf16(af[1][2], b02, c01, 0,0,0);\
      c10 = __builtin_amdgcn_mfma_f32_16x16x32_bf16(af[0][2], b12, c10, 0,0,0);\
      c11 = __builtin_amdgcn_mfma_f32_16x16x32_bf16(af[1][2], b12, c11, 0,0,0);\
      c00 = __builtin_amdgcn_mfma_f32_16x16x32_bf16(af[0][3], b03, c00, 0,0,0);\
      c01 = __builtin_amdgcn_mfma_f32_16x16x32_bf16(af[1][3], b03, c01, 0,0,0);\
      c10 = __builtin_amdgcn_mfma_f32_16x16x32_bf16(af[0][3], b13, c10, 0,0,0);\
      c11 = __builtin_amdgcn_mfma_f32_16x16x32_bf16(af[1][3], b13, c11, 0,0,0);\
      _Pragma("unroll")                                                        \
      for (int r = 0; r < 4; ++r) { /* C/D: col=lane&15, row=quad*4+r (m89) */ \
        float l, e;                                                            \
        l = c00[r]; e = EXP2(l);  /* log2-domain, |l|<=20.6: fp32-safe */      \
        Z0[r] += e; U0[r] = fmaf(e, l, U0[r]); V0[r] = fmaf(m0, e, V0[r]);     \
        l = c01[r]; e = EXP2(l);                                               \
        Z1[r] += e; U1[r] = fmaf(e, l, U1[r]); V1[r] = fmaf(m0, e, V1[r]);     \
        l = c10[r]; e = EXP2(l);                                               \
        Z0[r] += e; U0[r] = fmaf(e, l, U0[r]); V0[r] = fmaf(m1, e, V0[r]);     \
        l = c11[r]; e = EXP2(l);                                               \
        Z1[r] += e; U1[r] = fmaf(e, l, U1[r]); V1[r] = fmaf(m1, e, V1[r]);     \
      }                                                                        \
    }
    HALFTILE(0)
    HALFTILE(2)
#undef HALFTILE
    __syncthreads();  // drains stage(jt+1); protects overwritten buffer
  }
#undef STAGE

  // reduce across the 16 column-lanes sharing each output row, then atomics
#define EMIT(s, Zc, Uc, Vc)                                                    \
  {                                                                            \
    _Pragma("unroll")                                                          \
    for (int r = 0; r < 4; ++r) {                                              \
      float z = Zc[r], u = Uc[r], v0 = Vc[r];                                  \
      _Pragma("unroll")                                                        \
      for (int off = 1; off < 16; off <<= 1) {                                 \
        z += __shfl_xor(z, off);                                               \
        u += __shfl_xor(u, off);                                               \
        v0 += __shfl_xor(v0, off);                                             \
      }                                                                        \
      if (col == 0) {                                                          \
        int row = rbI * 256 + wave * 32 + s * 16 + quad * 4 + r;               \
        int lab = label[row];                                                  \
        float v = (lab == 0) ? v0 : (z - v0);                                  \
        atomicAdd(&Zr[row], z);                                                \
        atomicAdd(&Ur[row], u * LN2); /* log2-domain -> nats */                \
        atomicAdd(&Vr[row], v);                                                \
      }                                                                        \
    }                                                                          \
  }
  EMIT(0, Z0, U0, V0)
  EMIT(1, Z1, U1, V1)
#undef EMIT

  // ---- ticket finale: last block computes counts + dots + total loss ----
  __syncthreads();  // all this block's EMIT atomics issued (vmcnt drained)
  if (tid == 0) {
    int t = __hip_atomic_fetch_add(ticket, 1, __ATOMIC_ACQ_REL,
                                   __HIP_MEMORY_SCOPE_AGENT);
    lastf = (t == 511);
  }
  __syncthreads();
  if (!lastf) return;

  // All 512 blocks' device-scope atomics are at the coherence point.
  float* hs = (float*)tile;  // reuse LDS: h0 in [0..127], h1 in [128..255]
  if (tid < 256) {
    float h = 0.f;
#pragma unroll
    for (int i = 0; i < 16; ++i) h += gh16[i * 256 + tid];
    hs[tid] = h;
  }
  int c1i = 0;
#pragma unroll
  for (int k = 0; k < 16; ++k) c1i += label[k * 512 + tid];  // coalesced
#pragma unroll
  for (int off = 32; off; off >>= 1) c1i += __shfl_xor(c1i, off);
  if (lane == 0) credu[wave] = c1i;
  __syncthreads();  // hs + credu ready
  int c1t = 0;
#pragma unroll
  for (int w = 0; w < 8; ++w) c1t += credu[w];
  float c1 = (float)c1t, c0 = (float)(BS - c1t);

  // 3 dots of the class-sum vectors (threads 0..127, one dim each)
  float p00 = 0.f, p01 = 0.f, p11 = 0.f;
  if (tid < 128) {
    float h0d = hs[tid], h1d = hs[128 + tid];
    p00 = h0d * h0d; p01 = h0d * h1d; p11 = h1d * h1d;
  }
#pragma unroll
  for (int off = 32; off; off >>= 1) {
    p00 += __shfl_xor(p00, off);
    p01 += __shfl_xor(p01, off);
    p11 += __shfl_xor(p11, off);
  }
  if (lane == 0) { dred[wave] = p00; dred[8 + wave] = p01; dred[16 + wave] = p11; }

  // per-row sum: (U - V/c)/Z
  float rc0 = 1.f / c0, rc1 = 1.f / c1;
  float local = 0.f;
#pragma unroll
  for (int k = 0; k < 16; ++k) {
    int row = k * 512 + tid;
    int lab = label[row];
    float Z = __hip_atomic_load(&Zr[row], __ATOMIC_RELAXED, __HIP_MEMORY_SCOPE_AGENT);
    float U = __hip_atomic_load(&Ur[row], __ATOMIC_RELAXED, __HIP_MEMORY_SCOPE_AGENT);
    float V = __hip_atomic_load(&Vr[row], __ATOMIC_RELAXED, __HIP_MEMORY_SCOPE_AGENT);
    local += (U - V * (lab ? rc1 : rc0)) / Z;
  }
#pragma unroll
  for (int off = 32; off; off >>= 1) local += __shfl_xor(local, off);
  if (lane == 0) fredu[wave] = local;
  __syncthreads();
  if (tid == 0) {
    float se = __expf(scale[0]);
    float a0 = __expf(1.f / c0), a1 = __expf(1.f / c1);
    float rZq0 = 1.f / (c0 * a0 + ((float)BS - c0));
    float rZq1 = 1.f / (c1 * a1 + ((float)BS - c1));
    float d00 = dred[0] + dred[1], d01 = dred[8] + dred[9],
          d11 = dred[16] + dred[17];
    float rows = 0.f;
#pragma unroll
    for (int w = 0; w < 8; ++w) rows += fredu[w];
    // Σ loss_i = Σ a/Zq  −  Σ (S+(a−1)T)/Zq  +  Σ (U − V/c)/Z
    //   class sums: Σ_{c0} S = se·h0·(h0+h1) = se·(d00+d01); Σ_{c0} T = se·d00
    float stsum = se * (rZq0 * ((d00 + d01) + (a0 - 1.f) * d00) +
                        rZq1 * ((d01 + d11) + (a1 - 1.f) * d11));
    float total = c0 * a0 * rZq0 + c1 * a1 * rZq1 - stsum + rows;
    out[0] = total * (0.5f / (float)BS);
  }
}

extern "C" void kernel_launch(void* const* d_in, const int* in_sizes, int n_in,
                              void* d_out, int out_size, void* d_ws, size_t ws_size,
                              hipStream_t stream) {
  const float* data = (const float*)d_in[0];
  const float* scale = (const float*)d_in[1];
  const int* label = (const int*)d_in[2];
  char* ws = (char*)d_ws;
  // ws layout (bytes):
  //   0        xnbF bf16 fragment-order [8192*128]   2 MB
  //   2097152  Zr     f32 [8192]
  //   2129920  Ur     f32 [8192]
  //   2162688  Vr     f32 [8192]
  //   2195456  gh16   f32 [16][256]  (16-way split class sums)
  //   2211840  ticket int [1]
  //   2211872  mf     f32 [8192]
  char* xnbF = ws;
  float* Zr = (float*)(ws + 2097152);
  float* Ur = (float*)(ws + 2129920);
  float* Vr = (float*)(ws + 2162688);
  float* gh16 = (float*)(ws + 2195456);
  int* ticket = (int*)(ws + 2211840);
  float* mf = (float*)(ws + 2211872);

  // gh16 + ticket (16388 B); Zr/Ur/Vr/mf zeroed in k_norm; out stored by
  // k_main's last block.
  hipMemsetAsync(ws + 2195456, 0, 16388, stream);

  k_norm<<<512, 256, 0, stream>>>(data, label, xnbF, gh16, Zr, Ur, Vr, mf);
  k_main<<<512, 512, 0, stream>>>((const short*)xnbF, label, mf, scale, gh16,
                                  Zr, Ur, Vr, ticket, (float*)d_out);
}